// Round 5
// baseline (401.719 us; speedup 1.0000x reference)
//
#include <hip/hip_runtime.h>

#define NS 115              // contributing samples (S=116, last one unused)
#define WEPS 5e-5f          // per-sample color skip
#define LOG_TSKIP -6.9078f  // chunk1 skip when T < 1e-3

typedef float f32x4 __attribute__((ext_vector_type(4)));
typedef float f32x2 __attribute__((ext_vector_type(2)));

struct SH9 { float a,b,c,d,e,f,g,h,i; };

__device__ __forceinline__ f32x4 load4(const float* p) { f32x4 v; __builtin_memcpy(&v, p, 16); return v; }
__device__ __forceinline__ f32x2 load2(const float* p) { f32x2 v; __builtin_memcpy(&v, p, 8);  return v; }

// clamp position -> cell base index + per-axis weights (computed ONCE per sample,
// shared by the opacity and color evals)
__device__ __forceinline__ void pos_to_cell(float px, float py, float pz,
                                            int& ibase, float* wxs, float* wys, float* wzs) {
    px = fminf(fmaxf(px, 0.0f), 126.9999f);
    py = fminf(fmaxf(py, 0.0f), 126.9999f);
    pz = fminf(fmaxf(pz, 0.0f), 126.9999f);
    int ix = (int)px, iy = (int)py, iz = (int)pz;
    float wx = px - (float)ix, wy = py - (float)iy, wz = pz - (float)iz;
    ibase = (ix << 14) + (iy << 7) + iz;
    wxs[0] = 1.0f - wx; wxs[1] = wx;
    wys[0] = 1.0f - wy; wys[1] = wy;
    wzs[0] = 1.0f - wz; wzs[1] = wz;
}

// opacity trilerp on a precomputed cell; z-adjacent corners via dwordx2.
__device__ __forceinline__ float op_cell(int ibase, const float* wxs, const float* wys,
                                         const float* wzs, const float* __restrict__ opa) {
    float op = 0.0f;
    #pragma unroll
    for (int cx = 0; cx < 2; ++cx)
    #pragma unroll
    for (int cy = 0; cy < 2; ++cy) {
        int idx = ibase + (cx << 14) + (cy << 7);
        f32x2 pr = load2(opa + idx);
        float wxy = wxs[cx] * wys[cy];
        op = fmaf(wxy * wzs[0], pr.x, op);
        op = fmaf(wxy * wzs[1], pr.y, op);
    }
    return fminf(fmaxf(op, 0.0f), 100000.0f);
}

// per-lane color eval on a precomputed cell: 8 corners x triple 9-dot
// (cell layout is color-major [3][9] -> R=f0..8, G=f9..17, B=f18..26)
__device__ __forceinline__ void color_cell(int ibase, const float* wxs, const float* wys,
                                           const float* wzs, const float* __restrict__ grid,
                                           const SH9& sh,
                                           float& cr, float& cg, float& cb) {
    float r = 0.0f, g = 0.0f, b = 0.0f;
    #pragma unroll
    for (int cx = 0; cx < 2; ++cx)
    #pragma unroll
    for (int cy = 0; cy < 2; ++cy)
    #pragma unroll
    for (int cz = 0; cz < 2; ++cz) {
        int idx = ibase + (cx << 14) + (cy << 7) + cz;
        float wc = wxs[cx] * wys[cy] * wzs[cz];
        const float* cp = grid + (size_t)idx * 27;
        f32x4 v0 = load4(cp);
        f32x4 v1 = load4(cp + 4);
        f32x4 v2 = load4(cp + 8);
        f32x4 v3 = load4(cp + 12);
        f32x4 v4 = load4(cp + 16);
        f32x4 v5 = load4(cp + 20);
        f32x4 v6 = load4(cp + 23);
        float c0 = sh.a*v0.x + sh.b*v0.y + sh.c*v0.z + sh.d*v0.w
                 + sh.e*v1.x + sh.f*v1.y + sh.g*v1.z + sh.h*v1.w + sh.i*v2.x;
        float c1 = sh.a*v2.y + sh.b*v2.z + sh.c*v2.w + sh.d*v3.x
                 + sh.e*v3.y + sh.f*v3.z + sh.g*v3.w + sh.h*v4.x + sh.i*v4.y;
        float c2 = sh.a*v4.z + sh.b*v4.w + sh.c*v5.x + sh.d*v5.y
                 + sh.e*v5.z + sh.f*v5.w + sh.g*v6.y + sh.h*v6.z + sh.i*v6.w;
        r = fmaf(wc, c0, r);
        g = fmaf(wc, c1, g);
        b = fmaf(wc, c2, b);
    }
    cr = fminf(fmaxf(r + 0.5f, 0.0f), 100000.0f);
    cg = fminf(fmaxf(g + 0.5f, 0.0f), 100000.0f);
    cb = fminf(fmaxf(b + 0.5f, 0.0f), 100000.0f);
}

__device__ __forceinline__ float wave_incl_scan(float v, int lane) {
    #pragma unroll
    for (int off = 1; off < 64; off <<= 1) {
        float n = __shfl_up(v, (unsigned)off, 64);
        if (lane >= off) v += n;
    }
    return v;
}

__device__ __forceinline__ SH9 make_sh(float ddx, float ddy, float ddz) {
    SH9 sh;
    sh.a = 0.28209479177387814f;
    sh.b = -0.4886025119029199f * ddy;
    sh.c =  0.4886025119029199f * ddz;
    sh.d = -0.4886025119029199f * ddx;
    sh.e =  1.0925484305920792f * ddx * ddy;
    sh.f = -1.0925484305920792f * ddy * ddz;
    sh.g =  0.31539156525252005f * (2.0f*ddz*ddz - ddx*ddx - ddy*ddy);
    sh.h = -1.0925484305920792f * ddx * ddz;
    sh.i =  0.5462742152960396f * (ddx*ddx - ddy*ddy);
    return sh;
}

// ---- single fused kernel: wave per ray, lane = sample.
// chunk k: lane s gathers opacity, wave-scan -> w in-register; lanes with
// w > WEPS evaluate their sample's color per-lane (27-fma triple 9-dot on the
// color-major [3][9] cell), reusing the cell decomposition from the op eval.
__global__ __launch_bounds__(256) void fused_kernel(
    const float* __restrict__ x, const float* __restrict__ d,
    const float* __restrict__ tmin, const float* __restrict__ tmax,
    const float* __restrict__ opa, const float* __restrict__ grid,
    float* __restrict__ out, int nrays)
{
    int gtid = blockIdx.x * blockDim.x + threadIdx.x;
    int ray = __builtin_amdgcn_readfirstlane(gtid >> 6);
    int lane = threadIdx.x & 63;
    if (ray >= nrays) return;

    float ox = x[3*ray+0], oy = x[3*ray+1], oz = x[3*ray+2];
    float ddx = d[3*ray+0], ddy = d[3*ray+1], ddz = d[3*ray+2];
    float t0 = tmin[ray];
    float range = tmax[ray] - t0;
    float delta = range * 0.0078125f;
    SH9 sh = make_sh(ddx, ddy, ddz);

    float accR = 0.0f, accG = 0.0f, accB = 0.0f;

    // ---- chunk 0: samples 0..63 ----
    {
        float tt = range * (0.05f + (float)lane * 0.0078125f) + t0;
        float px = ox + tt*ddx, py = oy + tt*ddy, pz = oz + tt*ddz;
        int ib; float wxs[2], wys[2], wzs[2];
        pos_to_cell(px, py, pz, ib, wxs, wys, wzs);
        float opv = op_cell(ib, wxs, wys, wzs, opa);
        float dts = -delta * opv;
        float incl = wave_incl_scan(dts, lane);
        float cum = incl - dts;
        float total0 = __shfl(incl, 63, 64);
        float w0 = __expf(cum) * (1.0f - __expf(dts));
        if (w0 > WEPS) {
            float cr, cg, cb;
            color_cell(ib, wxs, wys, wzs, grid, sh, cr, cg, cb);
            accR = w0 * cr; accG = w0 * cg; accB = w0 * cb;
        }

        // ---- chunk 1: samples 64..114 ----
        if (total0 > LOG_TSKIP) {
            int s1 = 64 + lane;
            float dts1 = 0.0f;
            int ib1 = 0; float wxs1[2] = {0.f,0.f}, wys1[2] = {0.f,0.f}, wzs1[2] = {0.f,0.f};
            if (s1 < NS) {
                float t1s = range * (0.05f + (float)s1 * 0.0078125f) + t0;
                float qx = ox + t1s*ddx, qy = oy + t1s*ddy, qz = oz + t1s*ddz;
                pos_to_cell(qx, qy, qz, ib1, wxs1, wys1, wzs1);
                dts1 = -delta * op_cell(ib1, wxs1, wys1, wzs1, opa);
            }
            float incl1 = wave_incl_scan(dts1, lane);
            float cum1 = total0 + incl1 - dts1;
            float w1 = __expf(cum1) * (1.0f - __expf(dts1));   // ==0 for s1>=NS
            if (w1 > WEPS) {
                float cr, cg, cb;
                color_cell(ib1, wxs1, wys1, wzs1, grid, sh, cr, cg, cb);
                accR = fmaf(w1, cr, accR);
                accG = fmaf(w1, cg, accG);
                accB = fmaf(w1, cb, accB);
            }
        }
    }

    #pragma unroll
    for (int off = 32; off > 0; off >>= 1) {
        accR += __shfl_xor(accR, off, 64);
        accG += __shfl_xor(accG, off, 64);
        accB += __shfl_xor(accB, off, 64);
    }
    if (lane == 0) {
        out[3*ray+0] = accR;
        out[3*ray+1] = accG;
        out[3*ray+2] = accB;
    }
}

extern "C" void kernel_launch(void* const* d_in, const int* in_sizes, int n_in,
                              void* d_out, int out_size, void* d_ws, size_t ws_size,
                              hipStream_t stream) {
    const float* x    = (const float*)d_in[0];
    const float* d    = (const float*)d_in[1];
    const float* tmin = (const float*)d_in[2];
    const float* tmax = (const float*)d_in[3];
    const float* grid = (const float*)d_in[4];
    const float* opa  = (const float*)d_in[5];
    float* out = (float*)d_out;

    int nrays = in_sizes[0] / 3;                 // 32768
    int blocks = (nrays * 64 + 255) / 256;       // 8192

    (void)d_ws; (void)ws_size;
    fused_kernel<<<blocks, 256, 0, stream>>>(x, d, tmin, tmax, opa, grid, out, nrays);
}

// Round 6
// 380.951 us; speedup vs baseline: 1.0545x; 1.0545x over previous
//
#include <hip/hip_runtime.h>

#define NS 115              // contributing samples (S=116, last one unused)
#define WEPS 5e-5f          // per-sample color skip
#define LOG_TSKIP -6.9078f  // chunk1 skip when T < 1e-3

typedef float f32x4 __attribute__((ext_vector_type(4)));
typedef float f32x2 __attribute__((ext_vector_type(2)));

struct SH9 { float a,b,c,d,e,f,g,h,i; };

__device__ __forceinline__ f32x4 load4(const float* p) { f32x4 v; __builtin_memcpy(&v, p, 16); return v; }
__device__ __forceinline__ f32x2 load2(const float* p) { f32x2 v; __builtin_memcpy(&v, p, 8);  return v; }

__device__ __forceinline__ void pos_to_cell(float px, float py, float pz,
                                            int& ibase, float* wxs, float* wys, float* wzs) {
    px = fminf(fmaxf(px, 0.0f), 126.9999f);
    py = fminf(fmaxf(py, 0.0f), 126.9999f);
    pz = fminf(fmaxf(pz, 0.0f), 126.9999f);
    int ix = (int)px, iy = (int)py, iz = (int)pz;
    float wx = px - (float)ix, wy = py - (float)iy, wz = pz - (float)iz;
    ibase = (ix << 14) + (iy << 7) + iz;
    wxs[0] = 1.0f - wx; wxs[1] = wx;
    wys[0] = 1.0f - wy; wys[1] = wy;
    wzs[0] = 1.0f - wz; wzs[1] = wz;
}

// opacity trilerp; z-adjacent corners via dwordx2.
__device__ __forceinline__ float eval_op(float px, float py, float pz,
                                         const float* __restrict__ opa) {
    int ibase; float wxs[2], wys[2], wzs[2];
    pos_to_cell(px, py, pz, ibase, wxs, wys, wzs);
    float op = 0.0f;
    #pragma unroll
    for (int cx = 0; cx < 2; ++cx)
    #pragma unroll
    for (int cy = 0; cy < 2; ++cy) {
        int idx = ibase + (cx << 14) + (cy << 7);
        f32x2 pr = load2(opa + idx);
        float wxy = wxs[cx] * wys[cy];
        op = fmaf(wxy * wzs[0], pr.x, op);
        op = fmaf(wxy * wzs[1], pr.y, op);
    }
    return fminf(fmaxf(op, 0.0f), 100000.0f);
}

__device__ __forceinline__ float wave_incl_scan(float v, int lane) {
    #pragma unroll
    for (int off = 1; off < 64; off <<= 1) {
        float n = __shfl_up(v, (unsigned)off, 64);
        if (lane >= off) v += n;
    }
    return v;
}

__device__ __forceinline__ SH9 make_sh(float ddx, float ddy, float ddz) {
    SH9 sh;
    sh.a = 0.28209479177387814f;
    sh.b = -0.4886025119029199f * ddy;
    sh.c =  0.4886025119029199f * ddz;
    sh.d = -0.4886025119029199f * ddx;
    sh.e =  1.0925484305920792f * ddx * ddy;
    sh.f = -1.0925484305920792f * ddy * ddz;
    sh.g =  0.31539156525252005f * (2.0f*ddz*ddz - ddx*ddx - ddy*ddy);
    sh.h = -1.0925484305920792f * ddx * ddz;
    sh.i =  0.5462742152960396f * (ddx*ddx - ddy*ddy);
    return sh;
}

// ---- single fused kernel: op/scan + color, wave per ray, lane = sample.
// Color phase: QUAD-cooperative gather on the f32 grid with ALL 16 corner
// loads batched into registers BEFORE any FMA (deep memory-level parallelism;
// the kernel is latency-bound, round-5 evidence). __launch_bounds__(256,4)
// grants a 128-VGPR budget so the compiler keeps the batch in registers.
__global__ __launch_bounds__(256, 4) void fused_color_kernel(
    const float* __restrict__ x, const float* __restrict__ d,
    const float* __restrict__ tmin, const float* __restrict__ tmax,
    const float* __restrict__ opa, const float* __restrict__ grid,
    float* __restrict__ out, int nrays)
{
    int gtid = blockIdx.x * blockDim.x + threadIdx.x;
    int ray = __builtin_amdgcn_readfirstlane(gtid >> 6);
    int lane = threadIdx.x & 63;
    if (ray >= nrays) return;
    int qd  = lane >> 2;    // quad id: sample-within-pass
    int sub = lane & 3;     // channel-range within cell

    float ox = x[3*ray+0], oy = x[3*ray+1], oz = x[3*ray+2];
    float ddx = d[3*ray+0], ddy = d[3*ray+1], ddz = d[3*ray+2];
    float t0 = tmin[ray];
    float range = tmax[ray] - t0;
    float delta = range * 0.0078125f;
    SH9 sh = make_sh(ddx, ddy, ddz);

    // ---- op phase, chunk 0: samples 0..63 ----
    float tt = range * (0.05f + (float)lane * 0.0078125f) + t0;
    float px0 = ox + tt*ddx, py0 = oy + tt*ddy, pz0 = oz + tt*ddz;
    float opv = eval_op(px0, py0, pz0, opa);
    float dts = -delta * opv;
    float incl = wave_incl_scan(dts, lane);
    float cum = incl - dts;
    float total0 = __shfl(incl, 63, 64);
    float w0 = __expf(cum) * (1.0f - __expf(dts));

    // ---- op phase, chunk 1: samples 64..114 ----
    float w1 = 0.0f;
    if (total0 > LOG_TSKIP) {
        int s1 = 64 + lane;
        float dts1 = 0.0f;
        if (s1 < NS) {
            float t1s = range * (0.05f + (float)s1 * 0.0078125f) + t0;
            float qx = ox + t1s*ddx, qy = oy + t1s*ddy, qz = oz + t1s*ddz;
            dts1 = -delta * eval_op(qx, qy, qz, opa);
        }
        float incl1 = wave_incl_scan(dts1, lane);
        float cum1 = total0 + incl1 - dts1;
        w1 = __expf(cum1) * (1.0f - __expf(dts1));   // ==0 for s1>=NS
    }

    // ---- color phase: per-lane dual masked SH vectors ----
    // sub0: ch0-7  = R sh0-7          -> s0={a..h}, s1=0
    // sub1: ch8-15 = R sh8, G sh0-6   -> s0={i,0..}, s1={0,a..g}
    // sub2: ch16-23= G sh7-8, B sh0-5 -> s0={h,i,0..}, s1={0,0,a..f}
    // sub3: loads f23..f26; ch24-26 = B sh6-8 -> s0={0,g,h,i,0..}, s1=0
    float s00,s01,s02,s03,s04,s05,s06,s07;
    float s10,s11,s12,s13,s14,s15,s16,s17;
    if (sub == 0) {
        s00=sh.a;s01=sh.b;s02=sh.c;s03=sh.d;s04=sh.e;s05=sh.f;s06=sh.g;s07=sh.h;
        s10=0.f;s11=0.f;s12=0.f;s13=0.f;s14=0.f;s15=0.f;s16=0.f;s17=0.f;
    } else if (sub == 1) {
        s00=sh.i;s01=0.f;s02=0.f;s03=0.f;s04=0.f;s05=0.f;s06=0.f;s07=0.f;
        s10=0.f;s11=sh.a;s12=sh.b;s13=sh.c;s14=sh.d;s15=sh.e;s16=sh.f;s17=sh.g;
    } else if (sub == 2) {
        s00=sh.h;s01=sh.i;s02=0.f;s03=0.f;s04=0.f;s05=0.f;s06=0.f;s07=0.f;
        s10=0.f;s11=0.f;s12=sh.a;s13=sh.b;s14=sh.c;s15=sh.d;s16=sh.e;s17=sh.f;
    } else {
        s00=0.f;s01=sh.g;s02=sh.h;s03=sh.i;s04=0.f;s05=0.f;s06=0.f;s07=0.f;
        s10=0.f;s11=0.f;s12=0.f;s13=0.f;s14=0.f;s15=0.f;s16=0.f;s17=0.f;
    }
    int offa = (sub == 3) ? 23 : (sub << 3);
    int offb = (sub == 3) ? 23 : offa + 4;

    unsigned long long b0 = __ballot(w0 > WEPS);
    unsigned long long b1 = __ballot(w1 > WEPS);

    float accR = 0.0f, accG = 0.0f, accB = 0.0f;

    #pragma unroll 1
    for (int p = 0; p < 8; ++p) {
        unsigned long long bsel = (p < 4) ? b0 : b1;
        int shl = (p & 3) << 4;
        if (((bsel >> shl) & 0xFFFFull) == 0) continue;   // whole pass dead
        int s = (p << 4) + qd;                            // sample index
        float ws = __shfl((p < 4) ? w0 : w1, s & 63, 64); // quad-uniform
        if (ws > WEPS) {
            float st = range * (0.05f + (float)s * 0.0078125f) + t0;
            float px = ox + st*ddx, py = oy + st*ddy, pz = oz + st*ddz;
            int ibase; float wxs[2], wys[2], wzs[2];
            pos_to_cell(px, py, pz, ibase, wxs, wys, wzs);

            // ---- batch ALL 16 loads (8 corners x 2 f32x4) before any FMA ----
            f32x4 va[8], vb[8];
            #pragma unroll
            for (int c = 0; c < 8; ++c) {
                int cx = c >> 2, cy = (c >> 1) & 1, cz = c & 1;
                int idx = ibase + (cx << 14) + (cy << 7) + cz;
                const float* cp = grid + (size_t)idx * 27;
                va[c] = load4(cp + offa);
                vb[c] = load4(cp + offb);
            }

            float d0a = 0.0f, d1a = 0.0f;
            #pragma unroll
            for (int c = 0; c < 8; ++c) {
                int cx = c >> 2, cy = (c >> 1) & 1, cz = c & 1;
                float wc = wxs[cx] * wys[cy] * wzs[cz];
                float f0=va[c].x, f1=va[c].y, f2=va[c].z, f3=va[c].w;
                float f4=vb[c].x, f5=vb[c].y, f6=vb[c].z, f7=vb[c].w;
                float e0 = s00*f0 + s01*f1 + s02*f2 + s03*f3
                         + s04*f4 + s05*f5 + s06*f6 + s07*f7;
                float e1 = s10*f0 + s11*f1 + s12*f2 + s13*f3
                         + s14*f4 + s15*f5 + s16*f6 + s17*f7;
                d0a = fmaf(wc, e0, d0a);
                d1a = fmaf(wc, e1, d1a);
            }

            // route dual dots to colors (per-sub mapping)
            float rp = (sub < 2)  ? d0a : 0.0f;
            float gp = (sub == 1) ? d1a : ((sub == 2) ? d0a : 0.0f);
            float bp = (sub == 2) ? d1a : ((sub == 3) ? d0a : 0.0f);
            // quad reduce (all 4 quad-lanes active together)
            rp += __shfl_xor(rp, 1, 64); rp += __shfl_xor(rp, 2, 64);
            gp += __shfl_xor(gp, 1, 64); gp += __shfl_xor(gp, 2, 64);
            bp += __shfl_xor(bp, 1, 64); bp += __shfl_xor(bp, 2, 64);
            float cr = fminf(fmaxf(rp + 0.5f, 0.0f), 100000.0f);
            float cg = fminf(fmaxf(gp + 0.5f, 0.0f), 100000.0f);
            float cb = fminf(fmaxf(bp + 0.5f, 0.0f), 100000.0f);
            accR = fmaf(ws, cr, accR);
            accG = fmaf(ws, cg, accG);
            accB = fmaf(ws, cb, accB);
        }
    }

    // quad lanes hold identical acc -> reduce across quads only
    #pragma unroll
    for (int off = 4; off < 64; off <<= 1) {
        accR += __shfl_xor(accR, off, 64);
        accG += __shfl_xor(accG, off, 64);
        accB += __shfl_xor(accB, off, 64);
    }
    if (lane == 0) {
        out[3*ray+0] = accR;
        out[3*ray+1] = accG;
        out[3*ray+2] = accB;
    }
}

extern "C" void kernel_launch(void* const* d_in, const int* in_sizes, int n_in,
                              void* d_out, int out_size, void* d_ws, size_t ws_size,
                              hipStream_t stream) {
    const float* x    = (const float*)d_in[0];
    const float* d    = (const float*)d_in[1];
    const float* tmin = (const float*)d_in[2];
    const float* tmax = (const float*)d_in[3];
    const float* grid = (const float*)d_in[4];
    const float* opa  = (const float*)d_in[5];
    float* out = (float*)d_out;

    int nrays = in_sizes[0] / 3;                 // 32768
    int blocks = (nrays * 64 + 255) / 256;       // 8192

    (void)d_ws; (void)ws_size;
    fused_color_kernel<<<blocks, 256, 0, stream>>>(x, d, tmin, tmax, opa, grid, out, nrays);
}

// Round 7
// 374.521 us; speedup vs baseline: 1.0726x; 1.0172x over previous
//
#include <hip/hip_runtime.h>

#define NS 115              // contributing samples (S=116, last one unused)
#define WEPS 5e-5f          // per-sample color skip
#define LOG_TSKIP -6.9078f  // chunk1 skip when T < 1e-3

typedef float f32x4 __attribute__((ext_vector_type(4)));
typedef float f32x2 __attribute__((ext_vector_type(2)));

struct SH9 { float a,b,c,d,e,f,g,h,i; };

// ---- forced-MLP loads: volatile asm defs cannot be re-sunk into load-use
// order by the scheduler; all loads issued back-to-back stay in flight.
__device__ __forceinline__ f32x4 aload4(const float* p) {
    f32x4 v;
    asm volatile("global_load_dwordx4 %0, %1, off" : "=v"(v) : "v"(p));
    return v;
}
__device__ __forceinline__ f32x2 aload2(const float* p) {
    f32x2 v;
    asm volatile("global_load_dwordx2 %0, %1, off" : "=v"(v) : "v"(p));
    return v;
}
// drain + fence against FMA hoisting (rule 18: "memory" clobber does not
// order register-only consumers; sched_barrier does).
__device__ __forceinline__ void vwait0() {
    asm volatile("s_waitcnt vmcnt(0)" ::: "memory");
    __builtin_amdgcn_sched_barrier(0);
}

__device__ __forceinline__ void pos_to_cell(float px, float py, float pz,
                                            int& ibase, float* wxs, float* wys, float* wzs) {
    px = fminf(fmaxf(px, 0.0f), 126.9999f);
    py = fminf(fmaxf(py, 0.0f), 126.9999f);
    pz = fminf(fmaxf(pz, 0.0f), 126.9999f);
    int ix = (int)px, iy = (int)py, iz = (int)pz;
    float wx = px - (float)ix, wy = py - (float)iy, wz = pz - (float)iz;
    ibase = (ix << 14) + (iy << 7) + iz;
    wxs[0] = 1.0f - wx; wxs[1] = wx;
    wys[0] = 1.0f - wy; wys[1] = wy;
    wzs[0] = 1.0f - wz; wzs[1] = wz;
}

__device__ __forceinline__ float wave_incl_scan(float v, int lane) {
    #pragma unroll
    for (int off = 1; off < 64; off <<= 1) {
        float n = __shfl_up(v, (unsigned)off, 64);
        if (lane >= off) v += n;
    }
    return v;
}

__device__ __forceinline__ SH9 make_sh(float ddx, float ddy, float ddz) {
    SH9 sh;
    sh.a = 0.28209479177387814f;
    sh.b = -0.4886025119029199f * ddy;
    sh.c =  0.4886025119029199f * ddz;
    sh.d = -0.4886025119029199f * ddx;
    sh.e =  1.0925484305920792f * ddx * ddy;
    sh.f = -1.0925484305920792f * ddy * ddz;
    sh.g =  0.31539156525252005f * (2.0f*ddz*ddz - ddx*ddx - ddy*ddy);
    sh.h = -1.0925484305920792f * ddx * ddz;
    sh.i =  0.5462742152960396f * (ddx*ddx - ddy*ddy);
    return sh;
}

// weighted opacity from 4 preloaded corner-pairs
__device__ __forceinline__ float op_from(const f32x2& c00, const f32x2& c01,
                                         const f32x2& c10, const f32x2& c11,
                                         const float* wxs, const float* wys,
                                         const float* wzs) {
    float op = 0.0f;
    float w00 = wxs[0]*wys[0], w01 = wxs[0]*wys[1];
    float w10 = wxs[1]*wys[0], w11 = wxs[1]*wys[1];
    op = fmaf(w00*wzs[0], c00.x, op); op = fmaf(w00*wzs[1], c00.y, op);
    op = fmaf(w01*wzs[0], c01.x, op); op = fmaf(w01*wzs[1], c01.y, op);
    op = fmaf(w10*wzs[0], c10.x, op); op = fmaf(w10*wzs[1], c10.y, op);
    op = fmaf(w11*wzs[0], c11.x, op); op = fmaf(w11*wzs[1], c11.y, op);
    return fminf(fmaxf(op, 0.0f), 100000.0f);
}

// ---- single fused kernel: op/scan + color, wave per ray, lane = sample.
// Forced-MLP version: chunk0+chunk1 opacity loads (8x dwordx2) issued together
// before the scan; each color pass issues all 16 corner loads (asm dwordx4)
// before any FMA. One vmcnt(0)+sched_barrier per batch.
__global__ __launch_bounds__(256, 4) void fused_color_kernel(
    const float* __restrict__ x, const float* __restrict__ d,
    const float* __restrict__ tmin, const float* __restrict__ tmax,
    const float* __restrict__ opa, const float* __restrict__ grid,
    float* __restrict__ out, int nrays)
{
    int gtid = blockIdx.x * blockDim.x + threadIdx.x;
    int ray = __builtin_amdgcn_readfirstlane(gtid >> 6);
    int lane = threadIdx.x & 63;
    if (ray >= nrays) return;
    int qd  = lane >> 2;    // quad id: sample-within-pass
    int sub = lane & 3;     // channel-range within cell

    float ox = x[3*ray+0], oy = x[3*ray+1], oz = x[3*ray+2];
    float ddx = d[3*ray+0], ddy = d[3*ray+1], ddz = d[3*ray+2];
    float t0 = tmin[ray];
    float range = tmax[ray] - t0;
    float delta = range * 0.0078125f;
    SH9 sh = make_sh(ddx, ddy, ddz);

    // ---- op phase: issue chunk0 AND chunk1 gathers together (8 loads) ----
    float tt = range * (0.05f + (float)lane * 0.0078125f) + t0;
    float px0 = ox + tt*ddx, py0 = oy + tt*ddy, pz0 = oz + tt*ddz;
    int ib0; float wxs0[2], wys0[2], wzs0[2];
    pos_to_cell(px0, py0, pz0, ib0, wxs0, wys0, wzs0);

    int s1 = 64 + lane;
    float t1s = range * (0.05f + (float)s1 * 0.0078125f) + t0;
    float qx = ox + t1s*ddx, qy = oy + t1s*ddy, qz = oz + t1s*ddz;
    int ib1; float wxs1[2], wys1[2], wzs1[2];
    pos_to_cell(qx, qy, qz, ib1, wxs1, wys1, wzs1);   // clamped => always valid

    f32x2 a00 = aload2(opa + ib0);
    f32x2 a01 = aload2(opa + ib0 + (1 << 7));
    f32x2 a10 = aload2(opa + ib0 + (1 << 14));
    f32x2 a11 = aload2(opa + ib0 + (1 << 14) + (1 << 7));
    f32x2 b00 = aload2(opa + ib1);
    f32x2 b01 = aload2(opa + ib1 + (1 << 7));
    f32x2 b10 = aload2(opa + ib1 + (1 << 14));
    f32x2 b11 = aload2(opa + ib1 + (1 << 14) + (1 << 7));
    vwait0();

    // chunk 0: samples 0..63
    float opv0 = op_from(a00, a01, a10, a11, wxs0, wys0, wzs0);
    float dts = -delta * opv0;
    float incl = wave_incl_scan(dts, lane);
    float cum = incl - dts;
    float total0 = __shfl(incl, 63, 64);
    float w0 = __expf(cum) * (1.0f - __expf(dts));

    // chunk 1: samples 64..114 (loads already in registers)
    float w1 = 0.0f;
    if (total0 > LOG_TSKIP) {           // wave-uniform branch
        float opv1 = op_from(b00, b01, b10, b11, wxs1, wys1, wzs1);
        float dts1 = (s1 < NS) ? (-delta * opv1) : 0.0f;
        float incl1 = wave_incl_scan(dts1, lane);
        float cum1 = total0 + incl1 - dts1;
        w1 = __expf(cum1) * (1.0f - __expf(dts1));   // ==0 for s1>=NS
    }

    // ---- color phase: per-lane dual masked SH vectors ----
    // sub0: ch0-7  = R sh0-7          -> s0={a..h}, s1=0
    // sub1: ch8-15 = R sh8, G sh0-6   -> s0={i,0..}, s1={0,a..g}
    // sub2: ch16-23= G sh7-8, B sh0-5 -> s0={h,i,0..}, s1={0,0,a..f}
    // sub3: loads f23..f26; ch24-26 = B sh6-8 -> s0={0,g,h,i,0..}, s1=0
    float s00,s01,s02,s03,s04,s05,s06,s07;
    float s10,s11,s12,s13,s14,s15,s16,s17;
    if (sub == 0) {
        s00=sh.a;s01=sh.b;s02=sh.c;s03=sh.d;s04=sh.e;s05=sh.f;s06=sh.g;s07=sh.h;
        s10=0.f;s11=0.f;s12=0.f;s13=0.f;s14=0.f;s15=0.f;s16=0.f;s17=0.f;
    } else if (sub == 1) {
        s00=sh.i;s01=0.f;s02=0.f;s03=0.f;s04=0.f;s05=0.f;s06=0.f;s07=0.f;
        s10=0.f;s11=sh.a;s12=sh.b;s13=sh.c;s14=sh.d;s15=sh.e;s16=sh.f;s17=sh.g;
    } else if (sub == 2) {
        s00=sh.h;s01=sh.i;s02=0.f;s03=0.f;s04=0.f;s05=0.f;s06=0.f;s07=0.f;
        s10=0.f;s11=0.f;s12=sh.a;s13=sh.b;s14=sh.c;s15=sh.d;s16=sh.e;s17=sh.f;
    } else {
        s00=0.f;s01=sh.g;s02=sh.h;s03=sh.i;s04=0.f;s05=0.f;s06=0.f;s07=0.f;
        s10=0.f;s11=0.f;s12=0.f;s13=0.f;s14=0.f;s15=0.f;s16=0.f;s17=0.f;
    }
    int offa = (sub == 3) ? 23 : (sub << 3);
    int offb = (sub == 3) ? 23 : offa + 4;

    unsigned long long bal0 = __ballot(w0 > WEPS);
    unsigned long long bal1 = __ballot(w1 > WEPS);

    float accR = 0.0f, accG = 0.0f, accB = 0.0f;

    #pragma unroll 1
    for (int p = 0; p < 8; ++p) {
        unsigned long long bsel = (p < 4) ? bal0 : bal1;
        int shl = (p & 3) << 4;
        if (((bsel >> shl) & 0xFFFFull) == 0) continue;   // whole pass dead
        int s = (p << 4) + qd;                            // sample index
        float ws = __shfl((p < 4) ? w0 : w1, s & 63, 64); // quad-uniform
        if (ws > WEPS) {
            float st = range * (0.05f + (float)s * 0.0078125f) + t0;
            float px = ox + st*ddx, py = oy + st*ddy, pz = oz + st*ddz;
            int ibase; float wxs[2], wys[2], wzs[2];
            pos_to_cell(px, py, pz, ibase, wxs, wys, wzs);

            // ---- FORCE all 16 loads in flight before any FMA ----
            f32x4 va[8], vb[8];
            #pragma unroll
            for (int c = 0; c < 8; ++c) {
                int cx = c >> 2, cy = (c >> 1) & 1, cz = c & 1;
                int idx = ibase + (cx << 14) + (cy << 7) + cz;
                const float* cp = grid + (size_t)idx * 27;
                va[c] = aload4(cp + offa);
                vb[c] = aload4(cp + offb);
            }
            vwait0();

            float d0a = 0.0f, d1a = 0.0f;
            #pragma unroll
            for (int c = 0; c < 8; ++c) {
                int cx = c >> 2, cy = (c >> 1) & 1, cz = c & 1;
                float wc = wxs[cx] * wys[cy] * wzs[cz];
                float f0=va[c].x, f1=va[c].y, f2=va[c].z, f3=va[c].w;
                float f4=vb[c].x, f5=vb[c].y, f6=vb[c].z, f7=vb[c].w;
                float e0 = s00*f0 + s01*f1 + s02*f2 + s03*f3
                         + s04*f4 + s05*f5 + s06*f6 + s07*f7;
                float e1 = s10*f0 + s11*f1 + s12*f2 + s13*f3
                         + s14*f4 + s15*f5 + s16*f6 + s17*f7;
                d0a = fmaf(wc, e0, d0a);
                d1a = fmaf(wc, e1, d1a);
            }

            // route dual dots to colors (per-sub mapping)
            float rp = (sub < 2)  ? d0a : 0.0f;
            float gp = (sub == 1) ? d1a : ((sub == 2) ? d0a : 0.0f);
            float bp = (sub == 2) ? d1a : ((sub == 3) ? d0a : 0.0f);
            // quad reduce (all 4 quad-lanes active together)
            rp += __shfl_xor(rp, 1, 64); rp += __shfl_xor(rp, 2, 64);
            gp += __shfl_xor(gp, 1, 64); gp += __shfl_xor(gp, 2, 64);
            bp += __shfl_xor(bp, 1, 64); bp += __shfl_xor(bp, 2, 64);
            float cr = fminf(fmaxf(rp + 0.5f, 0.0f), 100000.0f);
            float cg = fminf(fmaxf(gp + 0.5f, 0.0f), 100000.0f);
            float cb = fminf(fmaxf(bp + 0.5f, 0.0f), 100000.0f);
            accR = fmaf(ws, cr, accR);
            accG = fmaf(ws, cg, accG);
            accB = fmaf(ws, cb, accB);
        }
    }

    // quad lanes hold identical acc -> reduce across quads only
    #pragma unroll
    for (int off = 4; off < 64; off <<= 1) {
        accR += __shfl_xor(accR, off, 64);
        accG += __shfl_xor(accG, off, 64);
        accB += __shfl_xor(accB, off, 64);
    }
    if (lane == 0) {
        out[3*ray+0] = accR;
        out[3*ray+1] = accG;
        out[3*ray+2] = accB;
    }
}

extern "C" void kernel_launch(void* const* d_in, const int* in_sizes, int n_in,
                              void* d_out, int out_size, void* d_ws, size_t ws_size,
                              hipStream_t stream) {
    const float* x    = (const float*)d_in[0];
    const float* d    = (const float*)d_in[1];
    const float* tmin = (const float*)d_in[2];
    const float* tmax = (const float*)d_in[3];
    const float* grid = (const float*)d_in[4];
    const float* opa  = (const float*)d_in[5];
    float* out = (float*)d_out;

    int nrays = in_sizes[0] / 3;                 // 32768
    int blocks = (nrays * 64 + 255) / 256;       // 8192

    (void)d_ws; (void)ws_size;
    fused_color_kernel<<<blocks, 256, 0, stream>>>(x, d, tmin, tmax, opa, grid, out, nrays);
}